// Round 5
// baseline (274.079 us; speedup 1.0000x reference)
//
#include <hip/hip_runtime.h>
#include <cstdint>
#include <cstddef>

#define D_     256
#define TWO_D  512
#define R_     16
#define N0_    8192
#define L_     6
#define NL_    8192
#define B_     512
#define TOTAL_ (N0_ + L_*NL_)

#define MT      16          // nodes (M) per layer block  -> 512 blocks, 2/CU
#define XPITCH  520         // bf16 elems per X row (512 + 8 pad)
#define HPITCH  264         // bf16 elems per H row (256 + 8 pad)
#define OPITCH  264         // out-stage pitch (reuses X buffer)

using short8 = __attribute__((ext_vector_type(8))) short;   // 8 bf16 (4 VGPRs)
using f32x4  = __attribute__((ext_vector_type(4))) float;   // 4 fp32 acc

__device__ __forceinline__ unsigned short f2bf(float f) {
    union { float f; unsigned u; } v; v.f = f;
    unsigned u = v.u;
    return (unsigned short)((u + 0x7FFFu + ((u >> 16) & 1u)) >> 16);  // RNE
}
__device__ __forceinline__ float bf2f(unsigned short h) {
    union { unsigned u; float f; } v; v.u = ((unsigned)h) << 16;
    return v.f;
}
__device__ __forceinline__ float softplus_f(float x) {
    return fmaxf(x, 0.0f) + log1pf(expf(-fabsf(x)));
}

// ---------------------------------------------------------------- prep ----
// in: [r][K][N] fp32 -> out: [r][N][K] bf16 (64x64 tiles via LDS)
__global__ void transpose_w_k(const float* __restrict__ in,
                              unsigned short* __restrict__ out,
                              int K, int N) {
    __shared__ unsigned short tile[64][65];
    int ktiles = K >> 6, ntiles = N >> 6;
    int tilesPer = ktiles * ntiles;
    int r  = blockIdx.x / tilesPer;
    int rm = blockIdx.x % tilesPer;
    int kt = rm / ntiles, nt = rm % ntiles;
    int t = threadIdx.x;
    const float* src = in + (size_t)r * K * N + (size_t)(kt * 64) * N + nt * 64;
    int c4 = t & 15, r0 = t >> 4;
    #pragma unroll
    for (int p = 0; p < 4; ++p) {
        int row = r0 + p * 16;
        float4 v = *(const float4*)(src + (size_t)row * N + c4 * 4);
        tile[row][c4 * 4 + 0] = f2bf(v.x);
        tile[row][c4 * 4 + 1] = f2bf(v.y);
        tile[row][c4 * 4 + 2] = f2bf(v.z);
        tile[row][c4 * 4 + 3] = f2bf(v.w);
    }
    __syncthreads();
    unsigned short* dst = out + ((size_t)r * N + nt * 64) * K + kt * 64;
    #pragma unroll
    for (int p = 0; p < 16; ++p) {
        int e = p * 256 + t;
        int n = e >> 6, k = e & 63;
        dst[(size_t)n * K + k] = tile[k][n];
    }
}

// storeb[:N0] = bf16(init_table[thax]); block 0 zeroes accum
__global__ void init_gather_k(const int* __restrict__ thax,
                              const float* __restrict__ table,
                              unsigned short* __restrict__ storeb,
                              float* __restrict__ accum) {
    if (blockIdx.x == 0 && threadIdx.x < 8) accum[threadIdx.x] = 0.0f;
    int gid = blockIdx.x * 256 + threadIdx.x;
    int row = gid >> 6;
    int c   = (gid & 63) * 4;
    int t   = thax[row];
    float4 v = *(const float4*)(table + (size_t)t * D_ + c);
    ushort4 o;
    o.x = f2bf(v.x); o.y = f2bf(v.y); o.z = f2bf(v.z); o.w = f2bf(v.w);
    *(ushort4*)(storeb + (size_t)row * D_ + c) = o;
}

// ---------------------------------------------------------------- layer ----
// 512 blocks x 512 threads (8 waves, n-slice 32/wave). Block = 16 nodes x
// full N=256 of one rule -> 2 blocks/CU, 16 waves/CU (4/SIMD) for latency
// hiding. Weights read directly from global (L2-resident; rule<->XCD swizzle
// keeps 2 rules = 768 KB per XCD). K-loops fully unrolled, no in-loop
// barriers -> compiler software-pipelines the independent b-loads.
__global__ __launch_bounds__(512, 4)
void layer_k(unsigned short* __restrict__ storeb,
             const int* __restrict__ par,              // this layer: [NL][2]
             const unsigned short* __restrict__ w1t,   // [R][256][512] bf16
             const unsigned short* __restrict__ w2t,   // [R][256][256] bf16
             const float* __restrict__ b1,
             const float* __restrict__ b2,
             int layer) {
    __shared__ unsigned short X[MT * XPITCH];   // 16640 B (also out-stage)
    __shared__ unsigned short H[MT * HPITCH];   //  8448 B

    int bid = blockIdx.x;
    int r   = (bid & 7) | (((bid >> 3) & 1) << 3);   // XCD-local rule
    int mt  = bid >> 4;                               // 0..31
    int tid = threadIdx.x;
    int nodeInLayer0 = r * B_ + mt * MT;

    int w    = tid >> 6;        // wave 0..7 -> n-slice base w*32
    int lane = tid & 63;
    int q    = lane >> 4;
    int ml   = lane & 15;
    int nb   = w * 32;

    const unsigned short* w1r = w1t + (size_t)r * D_ * TWO_D;
    const unsigned short* w2r = w2t + (size_t)r * D_ * D_;

    // gather parents -> X: 16 rows x 2 parents x 32 chunks = 1024, 2/thread
    int pidx[2];
    #pragma unroll
    for (int it = 0; it < 2; ++it) {
        int c = it * 512 + tid;
        pidx[it] = par[(nodeInLayer0 + (c >> 6)) * 2 + ((c & 63) >> 5)];
    }
    #pragma unroll
    for (int it = 0; it < 2; ++it) {
        int c   = it * 512 + tid;
        int m   = c >> 6;
        int rem = c & 63;
        int j   = rem >> 5;
        int c16 = rem & 31;
        uint4 v = *((const uint4*)(storeb + (size_t)pidx[it] * D_) + c16);
        *((uint4*)(&X[m * XPITCH + j * D_ + c16 * 8])) = v;
    }
    __syncthreads();

    // ---- GEMM1: [16 x 512] @ [512 x 256] -> H, relu(.+b1) ----
    f32x4 acc[2] = {};
    #pragma unroll
    for (int ks = 0; ks < 16; ++ks) {
        int k0 = ks * 32 + q * 8;
        short8 a = *(const short8*)(&X[ml * XPITCH + k0]);
        #pragma unroll
        for (int ni = 0; ni < 2; ++ni) {
            int n = nb + ni * 16 + ml;
            short8 b = *(const short8*)(&w1r[(size_t)n * TWO_D + k0]);
            acc[ni] = __builtin_amdgcn_mfma_f32_16x16x32_bf16(a, b, acc[ni], 0, 0, 0);
        }
    }
    #pragma unroll
    for (int ni = 0; ni < 2; ++ni) {
        int n = nb + ni * 16 + ml;
        float bias = b1[r * D_ + n];
        #pragma unroll
        for (int v = 0; v < 4; ++v) {
            int row = q * 4 + v;                 // C/D: row = quad*4+reg
            float x = acc[ni][v] + bias;
            H[row * HPITCH + n] = f2bf(x > 0.0f ? x : 0.0f);
        }
    }
    __syncthreads();

    // ---- GEMM2: [16 x 256] @ [256 x 256] (+b2) ----
    f32x4 acc2[2] = {};
    #pragma unroll
    for (int ks = 0; ks < 8; ++ks) {
        int k0 = ks * 32 + q * 8;
        short8 a = *(const short8*)(&H[ml * HPITCH + k0]);
        #pragma unroll
        for (int ni = 0; ni < 2; ++ni) {
            int n = nb + ni * 16 + ml;
            short8 b = *(const short8*)(&w2r[(size_t)n * D_ + k0]);
            acc2[ni] = __builtin_amdgcn_mfma_f32_16x16x32_bf16(a, b, acc2[ni], 0, 0, 0);
        }
    }
    // X reads finished before the post-GEMM1 barrier -> safe to reuse as
    // out-stage now (waves write disjoint [row][n] regions).
    #pragma unroll
    for (int ni = 0; ni < 2; ++ni) {
        int n = nb + ni * 16 + ml;
        float bias = b2[r * D_ + n];
        #pragma unroll
        for (int v = 0; v < 4; ++v) {
            int row = q * 4 + v;
            float x = acc2[ni][v] + bias;
            X[row * OPITCH + n] = f2bf(x);
        }
    }
    __syncthreads();
    // coalesced store: 16 rows x 512 B, one uint4 per thread
    size_t outBase = (size_t)(N0_ + layer * NL_ + nodeInLayer0);
    {
        int c   = tid;              // 0..511 = 16 rows x 32 chunks
        int m   = c >> 5;
        int c16 = c & 31;
        uint4 v = *((const uint4*)(&X[m * OPITCH]) + c16);
        *((uint4*)(storeb + (outBase + m) * D_) + c16) = v;
    }
}

// ---------------------------------------------------------------- eval ----
__global__ void eval_k(const unsigned short* __restrict__ storeb,
                       const float* __restrict__ eval_w,
                       const float* __restrict__ eval_b,
                       const float* __restrict__ pos_vals,
                       const float* __restrict__ neg_vals,
                       const float* __restrict__ pos_weight,
                       float* __restrict__ accum) {
    int lane = threadIdx.x & 63;
    int wid  = blockIdx.x * (blockDim.x >> 6) + (threadIdx.x >> 6);
    int nw   = gridDim.x * (blockDim.x >> 6);
    float ew0 = eval_w[lane * 4 + 0], ew1 = eval_w[lane * 4 + 1];
    float ew2 = eval_w[lane * 4 + 2], ew3 = eval_w[lane * 4 + 3];
    float pw = pos_weight[0], eb = eval_b[0];
    float loss = 0, posTot = 0, negTot = 0, posOK = 0, negOK = 0;

    for (int node = wid; node < TOTAL_; node += nw) {
        ushort4 v = *(const ushort4*)(storeb + (size_t)node * D_ + lane * 4);
        float s = bf2f(v.x) * ew0 + bf2f(v.y) * ew1 + bf2f(v.z) * ew2 + bf2f(v.w) * ew3;
        #pragma unroll
        for (int off = 32; off > 0; off >>= 1) s += __shfl_down(s, off);
        if (lane == 0) {
            float x   = s + eb;
            float pos = pos_vals[node], neg = neg_vals[node];
            float tot = pos + neg;
            if (tot > 0.0f) {
                float tgt = pos / fmaxf(tot, 1e-9f);
                loss += tot * (pw * tgt * softplus_f(-x) + (1.0f - tgt) * softplus_f(x));
                posTot += pos; negTot += neg;
                if (x >= 0.0f) posOK += pos; else negOK += neg;
            }
        }
    }
    __shared__ float sh[5];
    if (threadIdx.x == 0) { for (int i = 0; i < 5; ++i) sh[i] = 0.0f; }
    __syncthreads();
    if (lane == 0) {
        atomicAdd(&sh[0], loss); atomicAdd(&sh[1], posTot); atomicAdd(&sh[2], negTot);
        atomicAdd(&sh[3], posOK); atomicAdd(&sh[4], negOK);
    }
    __syncthreads();
    if (threadIdx.x < 5) atomicAdd(&accum[threadIdx.x], sh[threadIdx.x]);
}

__global__ void finalize_k(const float* __restrict__ accum, float* __restrict__ out) {
    if (threadIdx.x == 0) {
        float loss = accum[0], posTot = accum[1], negTot = accum[2];
        float posOK = accum[3], negOK = accum[4];
        out[0] = loss;
        out[1] = (posTot > 0.0f) ? posOK / fmaxf(posTot, 1e-9f) : 1.0f;
        out[2] = (negTot > 0.0f) ? negOK / fmaxf(negTot, 1e-9f) : 1.0f;
    }
}

// ---------------------------------------------------------------- launch ---
extern "C" void kernel_launch(void* const* d_in, const int* in_sizes, int n_in,
                              void* d_out, int out_size, void* d_ws, size_t ws_size,
                              hipStream_t stream) {
    const int*   thax       = (const int*)  d_in[0];
    const int*   par        = (const int*)  d_in[1];
    const float* pos_vals   = (const float*)d_in[2];
    const float* neg_vals   = (const float*)d_in[3];
    const float* init_table = (const float*)d_in[4];
    const float* W1         = (const float*)d_in[5];
    const float* b1         = (const float*)d_in[6];
    const float* W2         = (const float*)d_in[7];
    const float* b2         = (const float*)d_in[8];
    const float* eval_w     = (const float*)d_in[9];
    const float* eval_b     = (const float*)d_in[10];
    const float* pos_weight = (const float*)d_in[11];
    float* out = (float*)d_out;

    char* ws = (char*)d_ws;
    unsigned short* w1t    = (unsigned short*)(ws);                            // 4 MB
    unsigned short* w2t    = (unsigned short*)(ws + (size_t)4  * 1024 * 1024); // 2 MB
    unsigned short* storeb = (unsigned short*)(ws + (size_t)6  * 1024 * 1024); // 28 MB
    float*          accum  = (float*)(ws + (size_t)6 * 1024 * 1024 +
                                      (size_t)TOTAL_ * D_ * 2);

    hipLaunchKernelGGL(transpose_w_k, dim3(R_ * 8 * 4), dim3(256), 0, stream,
                       W1, w1t, TWO_D, D_);
    hipLaunchKernelGGL(transpose_w_k, dim3(R_ * 4 * 4), dim3(256), 0, stream,
                       W2, w2t, D_, D_);
    hipLaunchKernelGGL(init_gather_k, dim3(N0_ * 64 / 256), dim3(256), 0, stream,
                       thax, init_table, storeb, accum);
    for (int l = 0; l < L_; ++l) {
        hipLaunchKernelGGL(layer_k, dim3(512), dim3(512), 0, stream,
                           storeb, par + (size_t)l * NL_ * 2, w1t, w2t, b1, b2, l);
    }
    hipLaunchKernelGGL(eval_k, dim3(512), dim3(256), 0, stream,
                       storeb, eval_w, eval_b, pos_vals, neg_vals, pos_weight, accum);
    hipLaunchKernelGGL(finalize_k, dim3(1), dim3(1), 0, stream, accum, out);
}

// Round 6
// 173.561 us; speedup vs baseline: 1.5791x; 1.5791x over previous
//
#include <hip/hip_runtime.h>
#include <cstdint>
#include <cstddef>

#define D_     256
#define TWO_D  512
#define R_     16
#define N0_    8192
#define L_     6
#define NL_    8192
#define B_     512
#define TOTAL_ (N0_ + L_*NL_)

#define MT      32          // nodes (M) per layer block -> 256 blocks
#define XPITCH  520         // bf16 elems per X row (512 + 8 pad)
#define HPITCH  264         // bf16 elems per H row (256 + 8 pad)
#define OPITCH  264         // out-stage pitch (reuses X buffer)

using short8 = __attribute__((ext_vector_type(8))) short;   // 8 bf16 (4 VGPRs)
using f32x4  = __attribute__((ext_vector_type(4))) float;   // 4 fp32 acc

__device__ __forceinline__ unsigned short f2bf(float f) {
    union { float f; unsigned u; } v; v.f = f;
    unsigned u = v.u;
    return (unsigned short)((u + 0x7FFFu + ((u >> 16) & 1u)) >> 16);  // RNE
}
__device__ __forceinline__ float bf2f(unsigned short h) {
    union { unsigned u; float f; } v; v.u = ((unsigned)h) << 16;
    return v.f;
}
__device__ __forceinline__ float softplus_f(float x) {
    return fmaxf(x, 0.0f) + log1pf(expf(-fabsf(x)));
}

// ---------------------------------------------------------------- prep ----
// W [r][K][256] fp32  ->  fragment image [r][ks][q][n][8] bf16, where
// img(r,ks,q,n,j) = W[r][ks*32+q*8+j][n].  A wave's MFMA B-fragment load
// becomes 16B-per-lane CONTIGUOUS in n (fully-coalesced, full line use).
// Reads are coalesced too (lane n consecutive). Block = one (r,ks).
__global__ void wimg_k(const float* __restrict__ W,
                       unsigned short* __restrict__ img,
                       int KS, float* __restrict__ accum) {
    if (blockIdx.x == 0 && threadIdx.x < 8) accum[threadIdx.x] = 0.0f;
    int r  = blockIdx.x / KS;
    int ks = blockIdx.x - r * KS;
    const float* src = W + (size_t)r * KS * 32 * 256;
    #pragma unroll
    for (int it = 0; it < 4; ++it) {
        int item = it * 256 + threadIdx.x;      // 0..1023 = 4q x 256n
        int q = item >> 8, n = item & 255;
        short8 v;
        #pragma unroll
        for (int j = 0; j < 8; ++j)
            v[j] = (short)f2bf(src[(size_t)(ks * 32 + q * 8 + j) * 256 + n]);
        *(short8*)(img + ((((size_t)r * KS + ks) * 4 + q) * 256 + n) * 8) = v;
    }
}

// storeb[:N0] = bf16(init_table[thax])
__global__ void init_gather_k(const int* __restrict__ thax,
                              const float* __restrict__ table,
                              unsigned short* __restrict__ storeb) {
    int gid = blockIdx.x * 256 + threadIdx.x;
    int row = gid >> 6;
    int c   = (gid & 63) * 4;
    int t   = thax[row];
    float4 v = *(const float4*)(table + (size_t)t * D_ + c);
    ushort4 o;
    o.x = f2bf(v.x); o.y = f2bf(v.y); o.z = f2bf(v.z); o.w = f2bf(v.w);
    *(ushort4*)(storeb + (size_t)row * D_ + c) = o;
}

// ---------------------------------------------------------------- layer ----
// 256 blocks x 512 threads (8 waves, n-slice 32/wave). Block = 32 nodes x
// full N=256 of one rule. Weights read direct from the fragment image:
// each b-load is 4 runs x 256 B (16 fully-used lines) instead of the old
// 64-line 25%-use gather. K-loop fully unrolled, no in-loop barriers ->
// compiler software-pipelines the independent loads. Rule<->XCD swizzle
// keeps 2 rules (=768 KB image) per XCD L2.
__global__ __launch_bounds__(512, 2)
void layer_k(unsigned short* __restrict__ storeb,
             const int* __restrict__ par,               // this layer: [NL][2]
             const unsigned short* __restrict__ w1img,  // [R][16][4][256][8]
             const unsigned short* __restrict__ w2img,  // [R][8][4][256][8]
             const float* __restrict__ b1,
             const float* __restrict__ b2,
             int layer) {
    __shared__ unsigned short X[MT * XPITCH];   // 33280 B (also out-stage)
    __shared__ unsigned short H[MT * HPITCH];   // 16896 B

    int bid = blockIdx.x;
    int r   = (bid & 7) | (((bid >> 3) & 1) << 3);   // XCD-local rule
    int mt  = bid >> 4;
    int tid = threadIdx.x;
    int nodeInLayer0 = r * B_ + mt * MT;

    int w    = tid >> 6;        // wave 0..7 -> n-slice base w*32
    int lane = tid & 63;
    int q    = lane >> 4;
    int ml   = lane & 15;
    int nb   = w * 32;

    const unsigned short* w1r = w1img + (size_t)r * 16 * 4 * 256 * 8;
    const unsigned short* w2r = w2img + (size_t)r * 8 * 4 * 256 * 8;
    size_t fb = (size_t)(q * 256 + nb + ml) * 8;   // per-lane fragment base

    // gather parents -> X: 32 rows x 2 parents x 32 chunks = 2048, 4/thread
    int pidx[4];
    #pragma unroll
    for (int it = 0; it < 4; ++it) {
        int c = it * 512 + tid;
        pidx[it] = par[(nodeInLayer0 + (c >> 6)) * 2 + ((c & 63) >> 5)];
    }
    #pragma unroll
    for (int it = 0; it < 4; ++it) {
        int c   = it * 512 + tid;
        int m   = c >> 6;
        int rem = c & 63;
        int j   = rem >> 5;
        int c16 = rem & 31;
        uint4 v = *((const uint4*)(storeb + (size_t)pidx[it] * D_) + c16);
        *((uint4*)(&X[m * XPITCH + j * D_ + c16 * 8])) = v;
    }
    __syncthreads();

    // ---- GEMM1: [32 x 512] @ [512 x 256] -> H, relu(.+b1) ----
    f32x4 acc[2][2] = {};
    #pragma unroll
    for (int ks = 0; ks < 16; ++ks) {
        int k0 = ks * 32 + q * 8;
        short8 a0 = *(const short8*)(&X[ml * XPITCH + k0]);
        short8 a1 = *(const short8*)(&X[(16 + ml) * XPITCH + k0]);
        #pragma unroll
        for (int ni = 0; ni < 2; ++ni) {
            short8 b = *(const short8*)(&w1r[fb + (size_t)ks * 8192 + ni * 128]);
            acc[0][ni] = __builtin_amdgcn_mfma_f32_16x16x32_bf16(a0, b, acc[0][ni], 0, 0, 0);
            acc[1][ni] = __builtin_amdgcn_mfma_f32_16x16x32_bf16(a1, b, acc[1][ni], 0, 0, 0);
        }
    }
    #pragma unroll
    for (int ni = 0; ni < 2; ++ni) {
        int n = nb + ni * 16 + ml;
        float bias = b1[r * D_ + n];
        #pragma unroll
        for (int mi = 0; mi < 2; ++mi)
            #pragma unroll
            for (int v = 0; v < 4; ++v) {
                int row = mi * 16 + q * 4 + v;   // C/D: row = quad*4+reg
                float x = acc[mi][ni][v] + bias;
                H[row * HPITCH + n] = f2bf(x > 0.0f ? x : 0.0f);
            }
    }
    __syncthreads();

    // ---- GEMM2: [32 x 256] @ [256 x 256] (+b2) ----
    f32x4 acc2[2][2] = {};
    #pragma unroll
    for (int ks = 0; ks < 8; ++ks) {
        int k0 = ks * 32 + q * 8;
        short8 a0 = *(const short8*)(&H[ml * HPITCH + k0]);
        short8 a1 = *(const short8*)(&H[(16 + ml) * HPITCH + k0]);
        #pragma unroll
        for (int ni = 0; ni < 2; ++ni) {
            short8 b = *(const short8*)(&w2r[fb + (size_t)ks * 8192 + ni * 128]);
            acc2[0][ni] = __builtin_amdgcn_mfma_f32_16x16x32_bf16(a0, b, acc2[0][ni], 0, 0, 0);
            acc2[1][ni] = __builtin_amdgcn_mfma_f32_16x16x32_bf16(a1, b, acc2[1][ni], 0, 0, 0);
        }
    }
    // all X reads finished before post-GEMM1 barrier -> reuse X as out-stage
    #pragma unroll
    for (int ni = 0; ni < 2; ++ni) {
        int n = nb + ni * 16 + ml;
        float bias = b2[r * D_ + n];
        #pragma unroll
        for (int mi = 0; mi < 2; ++mi)
            #pragma unroll
            for (int v = 0; v < 4; ++v) {
                int row = mi * 16 + q * 4 + v;
                float x = acc2[mi][ni][v] + bias;
                X[row * OPITCH + n] = f2bf(x);
            }
    }
    __syncthreads();
    // coalesced store: 32 rows x 512 B, 2 uint4 per thread
    size_t outBase = (size_t)(N0_ + layer * NL_ + nodeInLayer0);
    #pragma unroll
    for (int it = 0; it < 2; ++it) {
        int c   = it * 512 + tid;       // 0..1023 = 32 rows x 32 chunks
        int m   = c >> 5;
        int c16 = c & 31;
        uint4 v = *((const uint4*)(&X[m * OPITCH]) + c16);
        *((uint4*)(storeb + (outBase + m) * D_) + c16) = v;
    }
}

// ---------------------------------------------------------------- eval ----
__global__ void eval_k(const unsigned short* __restrict__ storeb,
                       const float* __restrict__ eval_w,
                       const float* __restrict__ eval_b,
                       const float* __restrict__ pos_vals,
                       const float* __restrict__ neg_vals,
                       const float* __restrict__ pos_weight,
                       float* __restrict__ accum) {
    int lane = threadIdx.x & 63;
    int wid  = blockIdx.x * (blockDim.x >> 6) + (threadIdx.x >> 6);
    int nw   = gridDim.x * (blockDim.x >> 6);
    float ew0 = eval_w[lane * 4 + 0], ew1 = eval_w[lane * 4 + 1];
    float ew2 = eval_w[lane * 4 + 2], ew3 = eval_w[lane * 4 + 3];
    float pw = pos_weight[0], eb = eval_b[0];
    float loss = 0, posTot = 0, negTot = 0, posOK = 0, negOK = 0;

    for (int node = wid; node < TOTAL_; node += nw) {
        ushort4 v = *(const ushort4*)(storeb + (size_t)node * D_ + lane * 4);
        float s = bf2f(v.x) * ew0 + bf2f(v.y) * ew1 + bf2f(v.z) * ew2 + bf2f(v.w) * ew3;
        #pragma unroll
        for (int off = 32; off > 0; off >>= 1) s += __shfl_down(s, off);
        if (lane == 0) {
            float x   = s + eb;
            float pos = pos_vals[node], neg = neg_vals[node];
            float tot = pos + neg;
            if (tot > 0.0f) {
                float tgt = pos / fmaxf(tot, 1e-9f);
                loss += tot * (pw * tgt * softplus_f(-x) + (1.0f - tgt) * softplus_f(x));
                posTot += pos; negTot += neg;
                if (x >= 0.0f) posOK += pos; else negOK += neg;
            }
        }
    }
    __shared__ float sh[5];
    if (threadIdx.x == 0) { for (int i = 0; i < 5; ++i) sh[i] = 0.0f; }
    __syncthreads();
    if (lane == 0) {
        atomicAdd(&sh[0], loss); atomicAdd(&sh[1], posTot); atomicAdd(&sh[2], negTot);
        atomicAdd(&sh[3], posOK); atomicAdd(&sh[4], negOK);
    }
    __syncthreads();
    if (threadIdx.x < 5) atomicAdd(&accum[threadIdx.x], sh[threadIdx.x]);
}

__global__ void finalize_k(const float* __restrict__ accum, float* __restrict__ out) {
    if (threadIdx.x == 0) {
        float loss = accum[0], posTot = accum[1], negTot = accum[2];
        float posOK = accum[3], negOK = accum[4];
        out[0] = loss;
        out[1] = (posTot > 0.0f) ? posOK / fmaxf(posTot, 1e-9f) : 1.0f;
        out[2] = (negTot > 0.0f) ? negOK / fmaxf(negTot, 1e-9f) : 1.0f;
    }
}

// ---------------------------------------------------------------- launch ---
extern "C" void kernel_launch(void* const* d_in, const int* in_sizes, int n_in,
                              void* d_out, int out_size, void* d_ws, size_t ws_size,
                              hipStream_t stream) {
    const int*   thax       = (const int*)  d_in[0];
    const int*   par        = (const int*)  d_in[1];
    const float* pos_vals   = (const float*)d_in[2];
    const float* neg_vals   = (const float*)d_in[3];
    const float* init_table = (const float*)d_in[4];
    const float* W1         = (const float*)d_in[5];
    const float* b1         = (const float*)d_in[6];
    const float* W2         = (const float*)d_in[7];
    const float* b2         = (const float*)d_in[8];
    const float* eval_w     = (const float*)d_in[9];
    const float* eval_b     = (const float*)d_in[10];
    const float* pos_weight = (const float*)d_in[11];
    float* out = (float*)d_out;

    char* ws = (char*)d_ws;
    unsigned short* w1img  = (unsigned short*)(ws);                            // 4 MB
    unsigned short* w2img  = (unsigned short*)(ws + (size_t)4  * 1024 * 1024); // 2 MB
    unsigned short* storeb = (unsigned short*)(ws + (size_t)6  * 1024 * 1024); // 25 MB
    float*          accum  = (float*)(ws + (size_t)6 * 1024 * 1024 +
                                      (size_t)TOTAL_ * D_ * 2);

    hipLaunchKernelGGL(wimg_k, dim3(R_ * 16), dim3(256), 0, stream,
                       W1, w1img, 16, accum);
    hipLaunchKernelGGL(wimg_k, dim3(R_ * 8), dim3(256), 0, stream,
                       W2, w2img, 8, accum);
    hipLaunchKernelGGL(init_gather_k, dim3(N0_ * 64 / 256), dim3(256), 0, stream,
                       thax, init_table, storeb);
    for (int l = 0; l < L_; ++l) {
        hipLaunchKernelGGL(layer_k, dim3(256), dim3(512), 0, stream,
                           storeb, par + (size_t)l * NL_ * 2, w1img, w2img, b1, b2, l);
    }
    hipLaunchKernelGGL(eval_k, dim3(512), dim3(256), 0, stream,
                       storeb, eval_w, eval_b, pos_vals, neg_vals, pos_weight, accum);
    hipLaunchKernelGGL(finalize_k, dim3(1), dim3(1), 0, stream, accum, out);
}

// Round 7
// 172.326 us; speedup vs baseline: 1.5905x; 1.0072x over previous
//
#include <hip/hip_runtime.h>
#include <cstdint>
#include <cstddef>

#define D_     256
#define TWO_D  512
#define R_     16
#define N0_    8192
#define L_     6
#define NL_    8192
#define B_     512
#define TOTAL_ (N0_ + L_*NL_)

#define MT      32          // nodes (M) per layer block -> 256 blocks
#define XPITCH  520         // bf16 elems per X row (512 + 8 pad)
#define HPITCH  264         // bf16 elems per H row (256 + 8 pad)
#define OPITCH  264         // out-stage pitch (reuses X buffer)

using short8 = __attribute__((ext_vector_type(8))) short;   // 8 bf16 (4 VGPRs)
using f32x4  = __attribute__((ext_vector_type(4))) float;   // 4 fp32 acc

__device__ __forceinline__ unsigned short f2bf(float f) {
    union { float f; unsigned u; } v; v.f = f;
    unsigned u = v.u;
    return (unsigned short)((u + 0x7FFFu + ((u >> 16) & 1u)) >> 16);  // RNE
}
__device__ __forceinline__ float bf2f(unsigned short h) {
    union { unsigned u; float f; } v; v.u = ((unsigned)h) << 16;
    return v.f;
}
__device__ __forceinline__ float softplus_f(float x) {
    return fmaxf(x, 0.0f) + log1pf(expf(-fabsf(x)));
}

// ---------------------------------------------------------------- prep ----
// W [r][K][256] fp32  ->  fragment image [r][ks][q][n][8] bf16:
// img(r,ks,q,n,j) = W[r][ks*32+q*8+j][n]. Wave B-fragment loads become
// 4x256B contiguous runs (16 fully-used lines per instruction).
__global__ void wimg_k(const float* __restrict__ W,
                       unsigned short* __restrict__ img,
                       int KS, float* __restrict__ accum) {
    if (blockIdx.x == 0 && threadIdx.x < 8) accum[threadIdx.x] = 0.0f;
    int r  = blockIdx.x / KS;
    int ks = blockIdx.x - r * KS;
    const float* src = W + (size_t)r * KS * 32 * 256;
    #pragma unroll
    for (int it = 0; it < 4; ++it) {
        int item = it * 256 + threadIdx.x;      // 0..1023 = 4q x 256n
        int q = item >> 8, n = item & 255;
        short8 v;
        #pragma unroll
        for (int j = 0; j < 8; ++j)
            v[j] = (short)f2bf(src[(size_t)(ks * 32 + q * 8 + j) * 256 + n]);
        *(short8*)(img + ((((size_t)r * KS + ks) * 4 + q) * 256 + n) * 8) = v;
    }
}

// storeb[:N0] = bf16(init_table[thax])
__global__ void init_gather_k(const int* __restrict__ thax,
                              const float* __restrict__ table,
                              unsigned short* __restrict__ storeb) {
    int gid = blockIdx.x * 256 + threadIdx.x;
    int row = gid >> 6;
    int c   = (gid & 63) * 4;
    int t   = thax[row];
    float4 v = *(const float4*)(table + (size_t)t * D_ + c);
    ushort4 o;
    o.x = f2bf(v.x); o.y = f2bf(v.y); o.z = f2bf(v.z); o.w = f2bf(v.w);
    *(ushort4*)(storeb + (size_t)row * D_ + c) = o;
}

// ---------------------------------------------------------------- layer ----
// 256 blocks x 512 threads (8 waves, n-slice 32/wave). Block = 32 nodes x
// full N=256 of one rule. B-fragments are EXPLICITLY software-pipelined
// through a 16-slot register file (distance 8 K-steps): the main loop never
// waits a fresh global load. During GEMM1's 2nd half the freed slots are
// refilled with ALL W2 fragments, so GEMM2 has zero global loads.
__global__ __launch_bounds__(512, 2)
void layer_k(unsigned short* __restrict__ storeb,
             const int* __restrict__ par,               // this layer: [NL][2]
             const unsigned short* __restrict__ w1img,  // [R][16][4][256][8]
             const unsigned short* __restrict__ w2img,  // [R][8][4][256][8]
             const float* __restrict__ b1,
             const float* __restrict__ b2,
             int layer) {
    __shared__ unsigned short X[MT * XPITCH];   // 33280 B (also out-stage)
    __shared__ unsigned short H[MT * HPITCH];   // 16896 B

    int bid = blockIdx.x;
    int r   = (bid & 7) | (((bid >> 3) & 1) << 3);   // XCD-local rule
    int mt  = bid >> 4;
    int tid = threadIdx.x;
    int nodeInLayer0 = r * B_ + mt * MT;

    int w    = tid >> 6;        // wave 0..7 -> n-slice base w*32
    int lane = tid & 63;
    int q    = lane >> 4;
    int ml   = lane & 15;
    int nb   = w * 32;

    const unsigned short* w1r = w1img + (size_t)r * 16 * 4 * 256 * 8;
    const unsigned short* w2r = w2img + (size_t)r * 8 * 4 * 256 * 8;
    size_t fb = (size_t)(q * 256 + nb + ml) * 8;   // per-lane fragment base

    // --- B-fragment register file: preload W1 ks=0..7 (16 frags, 64 VGPR)
    short8 breg[16];
    #pragma unroll
    for (int p = 0; p < 8; ++p) {
        breg[p * 2 + 0] = *(const short8*)(&w1r[fb + (size_t)p * 8192]);
        breg[p * 2 + 1] = *(const short8*)(&w1r[fb + (size_t)p * 8192 + 128]);
    }

    // gather parents -> X: 32 rows x 2 parents x 32 chunks = 2048, 4/thread
    int pidx[4];
    #pragma unroll
    for (int it = 0; it < 4; ++it) {
        int c = it * 512 + tid;
        pidx[it] = par[(nodeInLayer0 + (c >> 6)) * 2 + ((c & 63) >> 5)];
    }
    #pragma unroll
    for (int it = 0; it < 4; ++it) {
        int c   = it * 512 + tid;
        int m   = c >> 6;
        int rem = c & 63;
        int j   = rem >> 5;
        int c16 = rem & 31;
        uint4 v = *((const uint4*)(storeb + (size_t)pidx[it] * D_) + c16);
        *((uint4*)(&X[m * XPITCH + j * D_ + c16 * 8])) = v;
    }
    __syncthreads();

    // ---- GEMM1: [32 x 512] @ [512 x 256] -> H, relu(.+b1) ----
    f32x4 acc[2][2] = {};
    #pragma unroll
    for (int ks = 0; ks < 16; ++ks) {
        int slot = (ks & 7) * 2;
        short8 b0 = breg[slot + 0];
        short8 b1f = breg[slot + 1];
        // refill slot: W1 frag ks+8 during first half, W2 frag ks-8 after
        if (ks < 8) {
            breg[slot + 0] = *(const short8*)(&w1r[fb + (size_t)(ks + 8) * 8192]);
            breg[slot + 1] = *(const short8*)(&w1r[fb + (size_t)(ks + 8) * 8192 + 128]);
        } else {
            breg[slot + 0] = *(const short8*)(&w2r[fb + (size_t)(ks - 8) * 8192]);
            breg[slot + 1] = *(const short8*)(&w2r[fb + (size_t)(ks - 8) * 8192 + 128]);
        }
        int k0 = ks * 32 + q * 8;
        short8 a0 = *(const short8*)(&X[ml * XPITCH + k0]);
        short8 a1 = *(const short8*)(&X[(16 + ml) * XPITCH + k0]);
        acc[0][0] = __builtin_amdgcn_mfma_f32_16x16x32_bf16(a0, b0,  acc[0][0], 0, 0, 0);
        acc[1][0] = __builtin_amdgcn_mfma_f32_16x16x32_bf16(a1, b0,  acc[1][0], 0, 0, 0);
        acc[0][1] = __builtin_amdgcn_mfma_f32_16x16x32_bf16(a0, b1f, acc[0][1], 0, 0, 0);
        acc[1][1] = __builtin_amdgcn_mfma_f32_16x16x32_bf16(a1, b1f, acc[1][1], 0, 0, 0);
    }
    #pragma unroll
    for (int ni = 0; ni < 2; ++ni) {
        int n = nb + ni * 16 + ml;
        float bias = b1[r * D_ + n];
        #pragma unroll
        for (int mi = 0; mi < 2; ++mi)
            #pragma unroll
            for (int v = 0; v < 4; ++v) {
                int row = mi * 16 + q * 4 + v;   // C/D: row = quad*4+reg
                float x = acc[mi][ni][v] + bias;
                H[row * HPITCH + n] = f2bf(x > 0.0f ? x : 0.0f);
            }
    }
    __syncthreads();

    // ---- GEMM2: [32 x 256] @ [256 x 256] (+b2) — B already in registers ----
    f32x4 acc2[2][2] = {};
    #pragma unroll
    for (int ks = 0; ks < 8; ++ks) {
        int slot = ks * 2;
        int k0 = ks * 32 + q * 8;
        short8 a0 = *(const short8*)(&H[ml * HPITCH + k0]);
        short8 a1 = *(const short8*)(&H[(16 + ml) * HPITCH + k0]);
        acc2[0][0] = __builtin_amdgcn_mfma_f32_16x16x32_bf16(a0, breg[slot + 0], acc2[0][0], 0, 0, 0);
        acc2[1][0] = __builtin_amdgcn_mfma_f32_16x16x32_bf16(a1, breg[slot + 0], acc2[1][0], 0, 0, 0);
        acc2[0][1] = __builtin_amdgcn_mfma_f32_16x16x32_bf16(a0, breg[slot + 1], acc2[0][1], 0, 0, 0);
        acc2[1][1] = __builtin_amdgcn_mfma_f32_16x16x32_bf16(a1, breg[slot + 1], acc2[1][1], 0, 0, 0);
    }
    // all X reads finished before post-GEMM1 barrier -> reuse X as out-stage
    #pragma unroll
    for (int ni = 0; ni < 2; ++ni) {
        int n = nb + ni * 16 + ml;
        float bias = b2[r * D_ + n];
        #pragma unroll
        for (int mi = 0; mi < 2; ++mi)
            #pragma unroll
            for (int v = 0; v < 4; ++v) {
                int row = mi * 16 + q * 4 + v;
                float x = acc2[mi][ni][v] + bias;
                X[row * OPITCH + n] = f2bf(x);
            }
    }
    __syncthreads();
    // coalesced store: 32 rows x 512 B, 2 uint4 per thread
    size_t outBase = (size_t)(N0_ + layer * NL_ + nodeInLayer0);
    #pragma unroll
    for (int it = 0; it < 2; ++it) {
        int c   = it * 512 + tid;       // 0..1023 = 32 rows x 32 chunks
        int m   = c >> 5;
        int c16 = c & 31;
        uint4 v = *((const uint4*)(&X[m * OPITCH]) + c16);
        *((uint4*)(storeb + (outBase + m) * D_) + c16) = v;
    }
}

// ---------------------------------------------------------------- eval ----
__global__ void eval_k(const unsigned short* __restrict__ storeb,
                       const float* __restrict__ eval_w,
                       const float* __restrict__ eval_b,
                       const float* __restrict__ pos_vals,
                       const float* __restrict__ neg_vals,
                       const float* __restrict__ pos_weight,
                       float* __restrict__ accum) {
    int lane = threadIdx.x & 63;
    int wid  = blockIdx.x * (blockDim.x >> 6) + (threadIdx.x >> 6);
    int nw   = gridDim.x * (blockDim.x >> 6);
    float ew0 = eval_w[lane * 4 + 0], ew1 = eval_w[lane * 4 + 1];
    float ew2 = eval_w[lane * 4 + 2], ew3 = eval_w[lane * 4 + 3];
    float pw = pos_weight[0], eb = eval_b[0];
    float loss = 0, posTot = 0, negTot = 0, posOK = 0, negOK = 0;

    for (int node = wid; node < TOTAL_; node += nw) {
        ushort4 v = *(const ushort4*)(storeb + (size_t)node * D_ + lane * 4);
        float s = bf2f(v.x) * ew0 + bf2f(v.y) * ew1 + bf2f(v.z) * ew2 + bf2f(v.w) * ew3;
        #pragma unroll
        for (int off = 32; off > 0; off >>= 1) s += __shfl_down(s, off);
        if (lane == 0) {
            float x   = s + eb;
            float pos = pos_vals[node], neg = neg_vals[node];
            float tot = pos + neg;
            if (tot > 0.0f) {
                float tgt = pos / fmaxf(tot, 1e-9f);
                loss += tot * (pw * tgt * softplus_f(-x) + (1.0f - tgt) * softplus_f(x));
                posTot += pos; negTot += neg;
                if (x >= 0.0f) posOK += pos; else negOK += neg;
            }
        }
    }
    __shared__ float sh[5];
    if (threadIdx.x == 0) { for (int i = 0; i < 5; ++i) sh[i] = 0.0f; }
    __syncthreads();
    if (lane == 0) {
        atomicAdd(&sh[0], loss); atomicAdd(&sh[1], posTot); atomicAdd(&sh[2], negTot);
        atomicAdd(&sh[3], posOK); atomicAdd(&sh[4], negOK);
    }
    __syncthreads();
    if (threadIdx.x < 5) atomicAdd(&accum[threadIdx.x], sh[threadIdx.x]);
}

__global__ void finalize_k(const float* __restrict__ accum, float* __restrict__ out) {
    if (threadIdx.x == 0) {
        float loss = accum[0], posTot = accum[1], negTot = accum[2];
        float posOK = accum[3], negOK = accum[4];
        out[0] = loss;
        out[1] = (posTot > 0.0f) ? posOK / fmaxf(posTot, 1e-9f) : 1.0f;
        out[2] = (negTot > 0.0f) ? negOK / fmaxf(negTot, 1e-9f) : 1.0f;
    }
}

// ---------------------------------------------------------------- launch ---
extern "C" void kernel_launch(void* const* d_in, const int* in_sizes, int n_in,
                              void* d_out, int out_size, void* d_ws, size_t ws_size,
                              hipStream_t stream) {
    const int*   thax       = (const int*)  d_in[0];
    const int*   par        = (const int*)  d_in[1];
    const float* pos_vals   = (const float*)d_in[2];
    const float* neg_vals   = (const float*)d_in[3];
    const float* init_table = (const float*)d_in[4];
    const float* W1         = (const float*)d_in[5];
    const float* b1         = (const float*)d_in[6];
    const float* W2         = (const float*)d_in[7];
    const float* b2         = (const float*)d_in[8];
    const float* eval_w     = (const float*)d_in[9];
    const float* eval_b     = (const float*)d_in[10];
    const float* pos_weight = (const float*)d_in[11];
    float* out = (float*)d_out;

    char* ws = (char*)d_ws;
    unsigned short* w1img  = (unsigned short*)(ws);                            // 4 MB
    unsigned short* w2img  = (unsigned short*)(ws + (size_t)4  * 1024 * 1024); // 2 MB
    unsigned short* storeb = (unsigned short*)(ws + (size_t)6  * 1024 * 1024); // 25 MB
    float*          accum  = (float*)(ws + (size_t)6 * 1024 * 1024 +
                                      (size_t)TOTAL_ * D_ * 2);

    hipLaunchKernelGGL(wimg_k, dim3(R_ * 16), dim3(256), 0, stream,
                       W1, w1img, 16, accum);
    hipLaunchKernelGGL(wimg_k, dim3(R_ * 8), dim3(256), 0, stream,
                       W2, w2img, 8, accum);
    hipLaunchKernelGGL(init_gather_k, dim3(N0_ * 64 / 256), dim3(256), 0, stream,
                       thax, init_table, storeb);
    for (int l = 0; l < L_; ++l) {
        hipLaunchKernelGGL(layer_k, dim3(256), dim3(512), 0, stream,
                           storeb, par + (size_t)l * NL_ * 2, w1img, w2img, b1, b2, l);
    }
    hipLaunchKernelGGL(eval_k, dim3(512), dim3(256), 0, stream,
                       storeb, eval_w, eval_b, pos_vals, neg_vals, pos_weight, accum);
    hipLaunchKernelGGL(finalize_k, dim3(1), dim3(1), 0, stream, accum, out);
}